// Round 13
// baseline (201.301 us; speedup 1.0000x reference)
//
#include <hip/hip_runtime.h>
#include <hip/hip_bf16.h>
#include <math.h>

#define NEG_SLOPE 0.2f
#define BK_BITS 9
#define BK (1 << BK_BITS)       // 512 dst per scatter bucket -> NB = 196
#define SBITS 17                // bits for src id (N=100000 < 2^17)
#define SMASK ((1 << SBITS) - 1)
#define CAP 20480               // pairs capacity per bucket (mean 16327, +32 sigma)
#define HRSTRIDE (CAP + 1024)   // csr region per HALF-bucket (256 dsts, rows padded x4)
#define EPB 2048                // edges per scatter block

__device__ __forceinline__ float lrelu(float x) { return x > 0.f ? x : NEG_SLOPE * x; }

// ==================== init bucket cursors ====================
__global__ void init_bcur(int* __restrict__ bcur, int NB) {
    int i = threadIdx.x;
    if (i < NB) bcur[i] = i * CAP;
}

// ==================== LDS-staged bucketed scatter (2048 edges/block) ==============
__global__ __launch_bounds__(256) void bucket_scatter(const int* __restrict__ src,
                                                      const int* __restrict__ dst,
                                                      int* __restrict__ bcur,
                                                      int* __restrict__ pairs, int E) {
    __shared__ int cnt[256], sc[256], off[256], cur[256], gbase[256];
    __shared__ int lpair[EPB];
    __shared__ unsigned char lbkt[EPB];
    int t = threadIdx.x;
    cnt[t] = 0;
    __syncthreads();

    int E4 = E >> 2;
    const int4* src4 = (const int4*)src;
    const int4* dst4 = (const int4*)dst;
    int base4 = blockIdx.x * (EPB / 4);
    int4 d4[2], s4[2];
    bool val[2];
#pragma unroll
    for (int k = 0; k < 2; k++) {
        int i4 = base4 + k * 256 + t;
        val[k] = (i4 < E4);
        if (val[k]) {
            d4[k] = dst4[i4];
            s4[k] = src4[i4];
            atomicAdd(&cnt[d4[k].x >> BK_BITS], 1);
            atomicAdd(&cnt[d4[k].y >> BK_BITS], 1);
            atomicAdd(&cnt[d4[k].z >> BK_BITS], 1);
            atomicAdd(&cnt[d4[k].w >> BK_BITS], 1);
        }
    }
    int dt = -1, st = 0;
    if (blockIdx.x == gridDim.x - 1) {
        int e = (E4 << 2) + t;
        if (e < E) { dt = dst[e]; st = src[e]; atomicAdd(&cnt[dt >> BK_BITS], 1); }
    }
    __syncthreads();

    sc[t] = cnt[t];
    __syncthreads();
    for (int o = 1; o < 256; o <<= 1) {
        int u = (t >= o) ? sc[t - o] : 0;
        __syncthreads();
        sc[t] += u;
        __syncthreads();
    }
    int excl = (t == 0) ? 0 : sc[t - 1];
    off[t] = excl;
    cur[t] = excl;
    if (cnt[t] > 0) gbase[t] = atomicAdd(&bcur[t], cnt[t]);
    __syncthreads();
    int total = sc[255];

#pragma unroll
    for (int k = 0; k < 2; k++) {
        if (val[k]) {
            int b, slot;
            b = d4[k].x >> BK_BITS; slot = atomicAdd(&cur[b], 1);
            lpair[slot] = ((d4[k].x & (BK - 1)) << SBITS) | s4[k].x; lbkt[slot] = (unsigned char)b;
            b = d4[k].y >> BK_BITS; slot = atomicAdd(&cur[b], 1);
            lpair[slot] = ((d4[k].y & (BK - 1)) << SBITS) | s4[k].y; lbkt[slot] = (unsigned char)b;
            b = d4[k].z >> BK_BITS; slot = atomicAdd(&cur[b], 1);
            lpair[slot] = ((d4[k].z & (BK - 1)) << SBITS) | s4[k].z; lbkt[slot] = (unsigned char)b;
            b = d4[k].w >> BK_BITS; slot = atomicAdd(&cur[b], 1);
            lpair[slot] = ((d4[k].w & (BK - 1)) << SBITS) | s4[k].w; lbkt[slot] = (unsigned char)b;
        }
    }
    if (dt >= 0) {
        int b = dt >> BK_BITS;
        int slot = atomicAdd(&cur[b], 1);
        lpair[slot] = ((dt & (BK - 1)) << SBITS) | st; lbkt[slot] = (unsigned char)b;
    }
    __syncthreads();

    for (int i = t; i < total; i += 256) {
        int b = lbkt[i];
        pairs[gbase[b] + (i - off[b])] = lpair[i];
    }
}

// ==================== CSR build: TWO blocks (1024 thr) per bucket ==================
// Block bh = 2*b + half handles dsts [b*512 + half*256, +256). Streams the bucket's
// pairs, filters its half. Rows padded to x4 in region bh*HRSTRIDE; pad = own dst.
__global__ __launch_bounds__(1024) void csr_build(const int* __restrict__ pairs,
                                                  const int* __restrict__ bcur,
                                                  int* __restrict__ row_deg,
                                                  int* __restrict__ csr_src, int N) {
    int bh = blockIdx.x;
    int b = bh >> 1, half = bh & 1;
    int t = threadIdx.x;
    int lo = b * CAP, hi = bcur[b];
    int dbase0 = (b << BK_BITS) + (half << 8);
    int ndst = min(256, N - dbase0);
    if (ndst <= 0) return;
    int base2 = bh * HRSTRIDE;
    __shared__ int cnt[256];
    __shared__ int sc[256];
    __shared__ int cur[256];
    if (t < 256) cnt[t] = 0;
    __syncthreads();
    for (int i = lo + t; i < hi; i += 1024) {
        int dl = pairs[i] >> SBITS;
        if ((dl >> 8) == half) atomicAdd(&cnt[dl & 255], 1);
    }
    __syncthreads();
    int d0 = 0, a0 = 0;
    if (t < 256) {
        d0 = (t < ndst) ? cnt[t] + 1 : 0;   // +1 self-loop
        a0 = (d0 + 3) & ~3;                 // padded
        sc[t] = a0;
    }
    __syncthreads();
    for (int o = 1; o < 256; o <<= 1) {
        int u = 0;
        if (t < 256 && t >= o) u = sc[t - o];
        __syncthreads();
        if (t < 256) sc[t] += u;
        __syncthreads();
    }
    if (t < ndst) {
        int excl = (t == 0) ? 0 : sc[t - 1];
        row_deg[dbase0 + t] = (excl << 16) | d0;
        csr_src[base2 + excl] = dbase0 + t;  // self-loop first
        for (int k = d0; k < a0; k++) csr_src[base2 + excl + k] = dbase0 + t;  // pad
        cur[t] = excl + 1;
    }
    __syncthreads();
    for (int i = lo + t; i < hi; i += 1024) {
        int p = pairs[i];
        int dl = p >> SBITS;
        if ((dl >> 8) == half) {
            int pos = atomicAdd(&cur[dl & 255], 1);
            csr_src[base2 + pos] = p & SMASK;
        }
    }
}

// ==================== fused layer1: 4 lanes per dst, register accumulate ==========
__global__ __launch_bounds__(256) void agg1_dstlane(
        const int* __restrict__ row_deg, const int* __restrict__ csr_src,
        const float2* __restrict__ x2,
        const float* __restrict__ W1, const float* __restrict__ asrc,
        const float* __restrict__ adst, const float* __restrict__ b1,
        const float* __restrict__ W2, const float* __restrict__ as2,
        const float* __restrict__ ad2,
        float2* __restrict__ h2, float* __restrict__ al2d, int N) {
    __shared__ float sW[64], sB[32], sW2[64], sP[4], sQ[4], sPd[4], sQd[4], sA2[4];
    int t = threadIdx.x;
    if (t < 64) { sW[t] = W1[t]; sW2[t] = W2[t]; }
    if (t < 32) sB[t] = b1[t];
    if (t < 2) { sA2[t] = as2[t]; sA2[2 + t] = ad2[t]; }
    if (t < 4) {
        float P = 0.f, Q = 0.f, Pd = 0.f, Qd = 0.f;
#pragma unroll
        for (int k = 0; k < 8; k++) {
            int c = t * 8 + k;
            float a = asrc[c], ad_ = adst[c];
            float w0 = W1[c], w1 = W1[32 + c];
            P += w0 * a; Q += w1 * a;
            Pd += w0 * ad_; Qd += w1 * ad_;
        }
        sP[t] = P; sQ[t] = Q; sPd[t] = Pd; sQd[t] = Qd;
    }
    __syncthreads();

    int tid = blockIdx.x * blockDim.x + t;
    int n = tid >> 2;
    int q = tid & 3;
    if (n >= N) return;
    int rd = row_deg[n];
    int row = (n >> 8) * HRSTRIDE + (rd >> 16);
    int deg = rd & 0xFFFF;

    float2 xd = x2[n];
    float P[4], Q[4], ald[4];
#pragma unroll
    for (int h = 0; h < 4; h++) {
        P[h] = sP[h]; Q[h] = sQ[h];
        ald[h] = xd.x * sPd[h] + xd.y * sQd[h];
    }

    float Sw[4] = {0.f, 0.f, 0.f, 0.f};
    float S0[4] = {0.f, 0.f, 0.f, 0.f};
    float S1[4] = {0.f, 0.f, 0.f, 0.f};
    for (int j = q * 4; j < deg; j += 16) {
        int4 s4 = *(const int4*)(csr_src + row + j);   // 16B-aligned
        float2 xs[4];
        xs[0] = x2[s4.x]; xs[1] = x2[s4.y]; xs[2] = x2[s4.z]; xs[3] = x2[s4.w];
#pragma unroll
        for (int k = 0; k < 4; k++) {
            bool live = (j + k < deg);
#pragma unroll
            for (int h = 0; h < 4; h++) {
                float e = lrelu(fmaf(xs[k].x, P[h], fmaf(xs[k].y, Q[h], ald[h])));
                float w = __expf(fminf(e, 80.f));
                w = live ? w : 0.f;
                Sw[h] += w;
                S0[h] += w * xs[k].x;
                S1[h] += w * xs[k].y;
            }
        }
    }
#pragma unroll
    for (int o = 1; o <= 2; o <<= 1) {
#pragma unroll
        for (int h = 0; h < 4; h++) {
            Sw[h] += __shfl_xor(Sw[h], o);
            S0[h] += __shfl_xor(S0[h], o);
            S1[h] += __shfl_xor(S1[h], o);
        }
    }
    if (q != 0) return;

    float r[4];
#pragma unroll
    for (int h = 0; h < 4; h++) r[h] = 1.f / (Sw[h] + 1e-16f);
    float h20 = 0.f, h21 = 0.f;
#pragma unroll
    for (int c = 0; c < 32; c++) {
        int h = c >> 3;
        float outc = (sW[c] * S0[h] + sW[32 + c] * S1[h]) * r[h];
        float v2 = outc + sB[c];
        v2 = v2 > 0.f ? v2 : __expf(v2) - 1.f;  // elu
        h20 = fmaf(v2, sW2[2 * c], h20);
        h21 = fmaf(v2, sW2[2 * c + 1], h21);
    }
    h2[n] = make_float2(h20, h21);
    al2d[n] = h20 * sA2[2] + h21 * sA2[3];
}

// ==================== layer 2 aggregate: 4 lanes per dst ====================
__global__ __launch_bounds__(256) void agg2_dstlane(
        const int* __restrict__ row_deg, const int* __restrict__ csr_src,
        const float* __restrict__ al2d, const float2* __restrict__ h2,
        const float* __restrict__ as2, const float* __restrict__ b2,
        float2* __restrict__ out, int N) {
    int tid = blockIdx.x * blockDim.x + threadIdx.x;
    int n = tid >> 2;
    int q = tid & 3;
    if (n >= N) return;
    int rd = row_deg[n];
    int row = (n >> 8) * HRSTRIDE + (rd >> 16);
    int deg = rd & 0xFFFF;
    float ald = al2d[n];
    float a0 = as2[0], a1 = as2[1];

    float wsum = 0.f, ax = 0.f, ay = 0.f;
    for (int j = q * 4; j < deg; j += 16) {
        int4 s4 = *(const int4*)(csr_src + row + j);
        float2 hv[4];
        hv[0] = h2[s4.x]; hv[1] = h2[s4.y]; hv[2] = h2[s4.z]; hv[3] = h2[s4.w];
#pragma unroll
        for (int k = 0; k < 4; k++) {
            float e = lrelu(fmaf(hv[k].x, a0, fmaf(hv[k].y, a1, ald)));
            float w = __expf(fminf(e, 80.f));
            w = (j + k < deg) ? w : 0.f;
            wsum += w;
            ax = fmaf(w, hv[k].x, ax);
            ay = fmaf(w, hv[k].y, ay);
        }
    }
#pragma unroll
    for (int o = 1; o <= 2; o <<= 1) {
        wsum += __shfl_xor(wsum, o);
        ax += __shfl_xor(ax, o);
        ay += __shfl_xor(ay, o);
    }
    if (q != 0) return;
    float inv = 1.f / (wsum + 1e-16f);
    out[n] = make_float2(ax * inv + b2[0], ay * inv + b2[1]);
}

extern "C" void kernel_launch(void* const* d_in, const int* in_sizes, int n_in,
                              void* d_out, int out_size, void* d_ws, size_t ws_size,
                              hipStream_t stream) {
    const float* x     = (const float*)d_in[0];
    const int*   eidx  = (const int*)d_in[1];
    const float* W1    = (const float*)d_in[3];
    const float* asrc1 = (const float*)d_in[4];
    const float* adst1 = (const float*)d_in[5];
    const float* b1    = (const float*)d_in[6];
    const float* W2    = (const float*)d_in[7];
    const float* asrc2 = (const float*)d_in[8];
    const float* adst2 = (const float*)d_in[9];
    const float* b2    = (const float*)d_in[10];

    const int N = in_sizes[0] / 2;   // 100000 (< 2^17 for packing)
    const int E = in_sizes[1] / 2;   // 3200000
    const int* src = eidx;
    const int* dst = eidx + E;
    const int NB = (N + BK - 1) >> BK_BITS;   // 196 scatter buckets
    const int NH = 2 * NB;                    // 392 csr half-buckets

    // -------- workspace layout --------
    float* w = (float*)d_ws;
    float2* h2    = (float2*)w;                 // 2N floats
    float*  al2d  = w + 2 * (size_t)N;          // N
    int* ip       = (int*)(w + 3 * (size_t)N);
    int* row_deg  = ip;                         // N
    int* bcur     = ip + (size_t)N;             // NB (padded to 200 for alignment)
    int* pairs    = ip + (size_t)N + 200;       // NB*CAP (4-aligned)
    int* csr_src  = pairs + (size_t)NB * CAP;   // NH*HRSTRIDE (16B-aligned)

    const int B = 256;
    int E4 = E >> 2;
    int gS = (E4 + (EPB / 4) - 1) / (EPB / 4);  // 2048 edges per block
    int gL4 = (4 * N + B - 1) / B;              // 4 lanes per dst

    init_bcur<<<1, B, 0, stream>>>(bcur, NB);
    bucket_scatter<<<gS, B, 0, stream>>>(src, dst, bcur, pairs, E);
    csr_build<<<NH, 1024, 0, stream>>>(pairs, bcur, row_deg, csr_src, N);

    agg1_dstlane<<<gL4, B, 0, stream>>>(row_deg, csr_src, (const float2*)x,
                                        W1, asrc1, adst1, b1, W2, asrc2, adst2,
                                        h2, al2d, N);
    agg2_dstlane<<<gL4, B, 0, stream>>>(row_deg, csr_src, al2d, h2, asrc2, b2,
                                        (float2*)d_out, N);
}

// Round 14
// 188.478 us; speedup vs baseline: 1.0680x; 1.0680x over previous
//
#include <hip/hip_runtime.h>
#include <hip/hip_bf16.h>
#include <math.h>

#define NEG_SLOPE 0.2f
#define BK_BITS 9
#define BK (1 << BK_BITS)       // 512 dst per scatter bucket -> NB = 196
#define SBITS 17                // bits for src id (N=100000 < 2^17)
#define SMASK ((1 << SBITS) - 1)
#define CAP 20480               // pairs capacity per bucket (mean 16327, +32 sigma)
#define HRSTRIDE (CAP + 1024)   // csr region per HALF-bucket (256 dsts, rows padded x4)

__device__ __forceinline__ float lrelu(float x) { return x > 0.f ? x : NEG_SLOPE * x; }

// ==================== init bucket cursors ====================
__global__ void init_bcur(int* __restrict__ bcur, int NB) {
    int i = threadIdx.x;
    if (i < NB) bcur[i] = i * CAP;
}

// ==================== LDS-staged bucketed scatter (4096 edges/block) ==============
__global__ __launch_bounds__(256) void bucket_scatter(const int* __restrict__ src,
                                                      const int* __restrict__ dst,
                                                      int* __restrict__ bcur,
                                                      int* __restrict__ pairs, int E) {
    __shared__ int cnt[256], sc[256], off[256], cur[256], gbase[256];
    __shared__ int lpair[4096];
    __shared__ unsigned char lbkt[4096];
    int t = threadIdx.x;
    cnt[t] = 0;
    __syncthreads();

    int E4 = E >> 2;
    const int4* src4 = (const int4*)src;
    const int4* dst4 = (const int4*)dst;
    int base4 = blockIdx.x * 1024;
    int4 d4[4], s4[4];
    bool val[4];
#pragma unroll
    for (int k = 0; k < 4; k++) {
        int i4 = base4 + k * 256 + t;
        val[k] = (i4 < E4);
        if (val[k]) {
            d4[k] = dst4[i4];
            s4[k] = src4[i4];
            atomicAdd(&cnt[d4[k].x >> BK_BITS], 1);
            atomicAdd(&cnt[d4[k].y >> BK_BITS], 1);
            atomicAdd(&cnt[d4[k].z >> BK_BITS], 1);
            atomicAdd(&cnt[d4[k].w >> BK_BITS], 1);
        }
    }
    int dt = -1, st = 0;
    if (blockIdx.x == gridDim.x - 1) {
        int e = (E4 << 2) + t;
        if (e < E) { dt = dst[e]; st = src[e]; atomicAdd(&cnt[dt >> BK_BITS], 1); }
    }
    __syncthreads();

    sc[t] = cnt[t];
    __syncthreads();
    for (int o = 1; o < 256; o <<= 1) {
        int u = (t >= o) ? sc[t - o] : 0;
        __syncthreads();
        sc[t] += u;
        __syncthreads();
    }
    int excl = (t == 0) ? 0 : sc[t - 1];
    off[t] = excl;
    cur[t] = excl;
    if (cnt[t] > 0) gbase[t] = atomicAdd(&bcur[t], cnt[t]);
    __syncthreads();
    int total = sc[255];

#pragma unroll
    for (int k = 0; k < 4; k++) {
        if (val[k]) {
            int b, slot;
            b = d4[k].x >> BK_BITS; slot = atomicAdd(&cur[b], 1);
            lpair[slot] = ((d4[k].x & (BK - 1)) << SBITS) | s4[k].x; lbkt[slot] = (unsigned char)b;
            b = d4[k].y >> BK_BITS; slot = atomicAdd(&cur[b], 1);
            lpair[slot] = ((d4[k].y & (BK - 1)) << SBITS) | s4[k].y; lbkt[slot] = (unsigned char)b;
            b = d4[k].z >> BK_BITS; slot = atomicAdd(&cur[b], 1);
            lpair[slot] = ((d4[k].z & (BK - 1)) << SBITS) | s4[k].z; lbkt[slot] = (unsigned char)b;
            b = d4[k].w >> BK_BITS; slot = atomicAdd(&cur[b], 1);
            lpair[slot] = ((d4[k].w & (BK - 1)) << SBITS) | s4[k].w; lbkt[slot] = (unsigned char)b;
        }
    }
    if (dt >= 0) {
        int b = dt >> BK_BITS;
        int slot = atomicAdd(&cur[b], 1);
        lpair[slot] = ((dt & (BK - 1)) << SBITS) | st; lbkt[slot] = (unsigned char)b;
    }
    __syncthreads();

    for (int i = t; i < total; i += 256) {
        int b = lbkt[i];
        pairs[gbase[b] + (i - off[b])] = lpair[i];
    }
}

// ==================== CSR build: TWO blocks (1024 thr) per bucket ==================
// Block bh = 2*b + half handles dsts [b*512 + half*256, +256). Streams the bucket's
// pairs, filters its half. Rows padded to x4 in region bh*HRSTRIDE; pad = own dst.
__global__ __launch_bounds__(1024) void csr_build(const int* __restrict__ pairs,
                                                  const int* __restrict__ bcur,
                                                  int* __restrict__ row_deg,
                                                  int* __restrict__ csr_src, int N) {
    int bh = blockIdx.x;
    int b = bh >> 1, half = bh & 1;
    int t = threadIdx.x;
    int lo = b * CAP, hi = bcur[b];
    int dbase0 = (b << BK_BITS) + (half << 8);
    int ndst = min(256, N - dbase0);
    if (ndst <= 0) return;
    int base2 = bh * HRSTRIDE;
    __shared__ int cnt[256];
    __shared__ int sc[256];
    __shared__ int cur[256];
    if (t < 256) cnt[t] = 0;
    __syncthreads();
    for (int i = lo + t; i < hi; i += 1024) {
        int dl = pairs[i] >> SBITS;
        if ((dl >> 8) == half) atomicAdd(&cnt[dl & 255], 1);
    }
    __syncthreads();
    int d0 = 0, a0 = 0;
    if (t < 256) {
        d0 = (t < ndst) ? cnt[t] + 1 : 0;   // +1 self-loop
        a0 = (d0 + 3) & ~3;                 // padded
        sc[t] = a0;
    }
    __syncthreads();
    for (int o = 1; o < 256; o <<= 1) {
        int u = 0;
        if (t < 256 && t >= o) u = sc[t - o];
        __syncthreads();
        if (t < 256) sc[t] += u;
        __syncthreads();
    }
    if (t < ndst) {
        int excl = (t == 0) ? 0 : sc[t - 1];
        row_deg[dbase0 + t] = (excl << 16) | d0;
        csr_src[base2 + excl] = dbase0 + t;  // self-loop first
        for (int k = d0; k < a0; k++) csr_src[base2 + excl + k] = dbase0 + t;  // pad
        cur[t] = excl + 1;
    }
    __syncthreads();
    for (int i = lo + t; i < hi; i += 1024) {
        int p = pairs[i];
        int dl = p >> SBITS;
        if ((dl >> 8) == half) {
            int pos = atomicAdd(&cur[dl & 255], 1);
            csr_src[base2 + pos] = p & SMASK;
        }
    }
}

// ==================== fused layer1: 4 lanes per dst, register accumulate ==========
__global__ __launch_bounds__(256) void agg1_dstlane(
        const int* __restrict__ row_deg, const int* __restrict__ csr_src,
        const float2* __restrict__ x2,
        const float* __restrict__ W1, const float* __restrict__ asrc,
        const float* __restrict__ adst, const float* __restrict__ b1,
        const float* __restrict__ W2, const float* __restrict__ as2,
        const float* __restrict__ ad2,
        float2* __restrict__ h2, float* __restrict__ al2d, int N) {
    __shared__ float sW[64], sB[32], sW2[64], sP[4], sQ[4], sPd[4], sQd[4], sA2[4];
    int t = threadIdx.x;
    if (t < 64) { sW[t] = W1[t]; sW2[t] = W2[t]; }
    if (t < 32) sB[t] = b1[t];
    if (t < 2) { sA2[t] = as2[t]; sA2[2 + t] = ad2[t]; }
    if (t < 4) {
        float P = 0.f, Q = 0.f, Pd = 0.f, Qd = 0.f;
#pragma unroll
        for (int k = 0; k < 8; k++) {
            int c = t * 8 + k;
            float a = asrc[c], ad_ = adst[c];
            float w0 = W1[c], w1 = W1[32 + c];
            P += w0 * a; Q += w1 * a;
            Pd += w0 * ad_; Qd += w1 * ad_;
        }
        sP[t] = P; sQ[t] = Q; sPd[t] = Pd; sQd[t] = Qd;
    }
    __syncthreads();

    int tid = blockIdx.x * blockDim.x + t;
    int n = tid >> 2;
    int q = tid & 3;
    if (n >= N) return;
    int rd = row_deg[n];
    int row = (n >> 8) * HRSTRIDE + (rd >> 16);
    int deg = rd & 0xFFFF;

    float2 xd = x2[n];
    float P[4], Q[4], ald[4];
#pragma unroll
    for (int h = 0; h < 4; h++) {
        P[h] = sP[h]; Q[h] = sQ[h];
        ald[h] = xd.x * sPd[h] + xd.y * sQd[h];
    }

    float Sw[4] = {0.f, 0.f, 0.f, 0.f};
    float S0[4] = {0.f, 0.f, 0.f, 0.f};
    float S1[4] = {0.f, 0.f, 0.f, 0.f};
    for (int j = q * 4; j < deg; j += 16) {
        int4 s4 = *(const int4*)(csr_src + row + j);   // 16B-aligned
        float2 xs[4];
        xs[0] = x2[s4.x]; xs[1] = x2[s4.y]; xs[2] = x2[s4.z]; xs[3] = x2[s4.w];
#pragma unroll
        for (int k = 0; k < 4; k++) {
            bool live = (j + k < deg);
#pragma unroll
            for (int h = 0; h < 4; h++) {
                float e = lrelu(fmaf(xs[k].x, P[h], fmaf(xs[k].y, Q[h], ald[h])));
                float w = __expf(fminf(e, 80.f));
                w = live ? w : 0.f;
                Sw[h] += w;
                S0[h] += w * xs[k].x;
                S1[h] += w * xs[k].y;
            }
        }
    }
#pragma unroll
    for (int o = 1; o <= 2; o <<= 1) {
#pragma unroll
        for (int h = 0; h < 4; h++) {
            Sw[h] += __shfl_xor(Sw[h], o);
            S0[h] += __shfl_xor(S0[h], o);
            S1[h] += __shfl_xor(S1[h], o);
        }
    }
    if (q != 0) return;

    float r[4];
#pragma unroll
    for (int h = 0; h < 4; h++) r[h] = 1.f / (Sw[h] + 1e-16f);
    float h20 = 0.f, h21 = 0.f;
#pragma unroll
    for (int c = 0; c < 32; c++) {
        int h = c >> 3;
        float outc = (sW[c] * S0[h] + sW[32 + c] * S1[h]) * r[h];
        float v2 = outc + sB[c];
        v2 = v2 > 0.f ? v2 : __expf(v2) - 1.f;  // elu
        h20 = fmaf(v2, sW2[2 * c], h20);
        h21 = fmaf(v2, sW2[2 * c + 1], h21);
    }
    h2[n] = make_float2(h20, h21);
    al2d[n] = h20 * sA2[2] + h21 * sA2[3];
}

// ==================== layer 2 aggregate: 4 lanes per dst ====================
__global__ __launch_bounds__(256) void agg2_dstlane(
        const int* __restrict__ row_deg, const int* __restrict__ csr_src,
        const float* __restrict__ al2d, const float2* __restrict__ h2,
        const float* __restrict__ as2, const float* __restrict__ b2,
        float2* __restrict__ out, int N) {
    int tid = blockIdx.x * blockDim.x + threadIdx.x;
    int n = tid >> 2;
    int q = tid & 3;
    if (n >= N) return;
    int rd = row_deg[n];
    int row = (n >> 8) * HRSTRIDE + (rd >> 16);
    int deg = rd & 0xFFFF;
    float ald = al2d[n];
    float a0 = as2[0], a1 = as2[1];

    float wsum = 0.f, ax = 0.f, ay = 0.f;
    for (int j = q * 4; j < deg; j += 16) {
        int4 s4 = *(const int4*)(csr_src + row + j);
        float2 hv[4];
        hv[0] = h2[s4.x]; hv[1] = h2[s4.y]; hv[2] = h2[s4.z]; hv[3] = h2[s4.w];
#pragma unroll
        for (int k = 0; k < 4; k++) {
            float e = lrelu(fmaf(hv[k].x, a0, fmaf(hv[k].y, a1, ald)));
            float w = __expf(fminf(e, 80.f));
            w = (j + k < deg) ? w : 0.f;
            wsum += w;
            ax = fmaf(w, hv[k].x, ax);
            ay = fmaf(w, hv[k].y, ay);
        }
    }
#pragma unroll
    for (int o = 1; o <= 2; o <<= 1) {
        wsum += __shfl_xor(wsum, o);
        ax += __shfl_xor(ax, o);
        ay += __shfl_xor(ay, o);
    }
    if (q != 0) return;
    float inv = 1.f / (wsum + 1e-16f);
    out[n] = make_float2(ax * inv + b2[0], ay * inv + b2[1]);
}

extern "C" void kernel_launch(void* const* d_in, const int* in_sizes, int n_in,
                              void* d_out, int out_size, void* d_ws, size_t ws_size,
                              hipStream_t stream) {
    const float* x     = (const float*)d_in[0];
    const int*   eidx  = (const int*)d_in[1];
    const float* W1    = (const float*)d_in[3];
    const float* asrc1 = (const float*)d_in[4];
    const float* adst1 = (const float*)d_in[5];
    const float* b1    = (const float*)d_in[6];
    const float* W2    = (const float*)d_in[7];
    const float* asrc2 = (const float*)d_in[8];
    const float* adst2 = (const float*)d_in[9];
    const float* b2    = (const float*)d_in[10];

    const int N = in_sizes[0] / 2;   // 100000 (< 2^17 for packing)
    const int E = in_sizes[1] / 2;   // 3200000
    const int* src = eidx;
    const int* dst = eidx + E;
    const int NB = (N + BK - 1) >> BK_BITS;   // 196 scatter buckets
    const int NH = 2 * NB;                    // 392 csr half-buckets

    // -------- workspace layout --------
    float* w = (float*)d_ws;
    float2* h2    = (float2*)w;                 // 2N floats
    float*  al2d  = w + 2 * (size_t)N;          // N
    int* ip       = (int*)(w + 3 * (size_t)N);
    int* row_deg  = ip;                         // N
    int* bcur     = ip + (size_t)N;             // NB (padded to 200 for alignment)
    int* pairs    = ip + (size_t)N + 200;       // NB*CAP (4-aligned)
    int* csr_src  = pairs + (size_t)NB * CAP;   // NH*HRSTRIDE (16B-aligned)

    const int B = 256;
    int E4 = E >> 2;
    int gS = (E4 + 1023) / 1024;                // 4096 edges per block
    int gL4 = (4 * N + B - 1) / B;              // 4 lanes per dst

    init_bcur<<<1, B, 0, stream>>>(bcur, NB);
    bucket_scatter<<<gS, B, 0, stream>>>(src, dst, bcur, pairs, E);
    csr_build<<<NH, 1024, 0, stream>>>(pairs, bcur, row_deg, csr_src, N);

    agg1_dstlane<<<gL4, B, 0, stream>>>(row_deg, csr_src, (const float2*)x,
                                        W1, asrc1, adst1, b1, W2, asrc2, adst2,
                                        h2, al2d, N);
    agg2_dstlane<<<gL4, B, 0, stream>>>(row_deg, csr_src, al2d, h2, asrc2, b2,
                                        (float2*)d_out, N);
}